// Round 1
// baseline (196.214 us; speedup 1.0000x reference)
//
#include <hip/hip_runtime.h>
#include <hip/hip_bf16.h>
#include <stdint.h>

#define NQ 16384   // 128*128 guide positions
#define NL 1024    // 32*32 low positions
#define DM 512

typedef __bf16 bf16_t;
typedef __bf16 bf16x8 __attribute__((ext_vector_type(8)));
typedef __bf16 bf16x4 __attribute__((ext_vector_type(4)));
typedef float f32x4 __attribute__((ext_vector_type(4)));

__device__ __forceinline__ void gload_lds16(const void* g, void* l) {
  __builtin_amdgcn_global_load_lds(
      (const __attribute__((address_space(1))) uint32_t*)g,
      (__attribute__((address_space(3))) uint32_t*)l, 16, 0, 0);
}

// ---------------- transpose (d-major fp32) -> (n-major bf16) ----------------
// src: [512][ncols] fp32, dst: [ncols][512] bf16
__global__ __launch_bounds__(256) void cvt_transpose(const float* __restrict__ src,
                                                     bf16_t* __restrict__ dst, int ncols) {
  __shared__ float tl[32][33];
  const int n0 = blockIdx.x * 32, c0 = blockIdx.y * 32;
  const int t = threadIdx.x, c = t & 31, r = t >> 5;  // r = 0..7
#pragma unroll
  for (int it = 0; it < 4; ++it) {
    int rr = r + it * 8;  // channel-within-tile
    tl[rr][c] = src[(size_t)(c0 + rr) * ncols + n0 + c];
  }
  __syncthreads();
#pragma unroll
  for (int it = 0; it < 4; ++it) {
    int rr = r + it * 8;  // n-within-tile
    dst[(size_t)(n0 + rr) * 512 + c0 + c] = (bf16_t)tl[c][rr];
  }
}

// ---------------- weights fp32 -> bf16 (4 matrices) ----------------
__global__ __launch_bounds__(256) void cvt_w(const float* __restrict__ s0, const float* __restrict__ s1,
                                             const float* __restrict__ s2, const float* __restrict__ s3,
                                             bf16_t* __restrict__ d0, bf16_t* __restrict__ d1,
                                             bf16_t* __restrict__ d2, bf16_t* __restrict__ d3) {
  const float* s;
  bf16_t* d;
  switch (blockIdx.y) {
    case 0: s = s0; d = d0; break;
    case 1: s = s1; d = d1; break;
    case 2: s = s2; d = d2; break;
    default: s = s3; d = d3; break;
  }
  const int i = (blockIdx.x * 256 + threadIdx.x) * 4;
  float4 v = *(const float4*)(s + i);
  bf16x4 o = {(bf16_t)v.x, (bf16_t)v.y, (bf16_t)v.z, (bf16_t)v.w};
  *(bf16x4*)(d + i) = o;
}

// ---------------- C = A(MxK) * B(NxK)^T, bf16 in, OutT out ----------------
// m97-pattern: 128x128 tile, BK=64, 4 waves (2x2), 16x16x32 bf16 MFMA
template <typename OutT>
__global__ __launch_bounds__(256) void gemm_bt(const bf16_t* __restrict__ A,
                                               const bf16_t* __restrict__ B,
                                               OutT* __restrict__ C, int M, int N, int K) {
  __shared__ __align__(16) bf16_t As[128 * 64];
  __shared__ __align__(16) bf16_t Bs[128 * 64];
  const int t = threadIdx.x;
  const int lane = t & 63;
  const int wave = t >> 6;
  const int wr = (wave >> 1) * 64;
  const int wc = (wave & 1) * 64;
  const int bm = blockIdx.x * 128;
  const int bn = blockIdx.y * 128;
  const int r0 = t >> 3;            // staging row within 32-row chunk
  const int c0 = (t & 7) * 8;       // staging col (elements)
  f32x4 acc[4][4] = {};
  for (int k0 = 0; k0 < K; k0 += 64) {
#pragma unroll
    for (int it = 0; it < 4; ++it) {
      const int r = r0 + it * 32;
      gload_lds16(A + (size_t)(bm + r) * K + k0 + c0, &As[r * 64 + c0]);
      gload_lds16(B + (size_t)(bn + r) * K + k0 + c0, &Bs[r * 64 + c0]);
    }
    __syncthreads();
#pragma unroll
    for (int kk = 0; kk < 2; ++kk) {
      bf16x8 af[4], bfv[4];
#pragma unroll
      for (int i = 0; i < 4; ++i)
        af[i] = *(const bf16x8*)&As[(wr + i * 16 + (lane & 15)) * 64 + kk * 32 + (lane >> 4) * 8];
#pragma unroll
      for (int i = 0; i < 4; ++i)
        bfv[i] = *(const bf16x8*)&Bs[(wc + i * 16 + (lane & 15)) * 64 + kk * 32 + (lane >> 4) * 8];
#pragma unroll
      for (int i = 0; i < 4; ++i)
#pragma unroll
        for (int j = 0; j < 4; ++j)
          acc[i][j] = __builtin_amdgcn_mfma_f32_16x16x32_bf16(af[i], bfv[j], acc[i][j], 0, 0, 0);
    }
    __syncthreads();
  }
  const int crow = bm + wr + ((lane >> 4) * 4);
  const int ccol = bn + wc + (lane & 15);
#pragma unroll
  for (int i = 0; i < 4; ++i)
#pragma unroll
    for (int j = 0; j < 4; ++j) {
      const int row = crow + i * 16;
      const int col = ccol + j * 16;
#pragma unroll
      for (int v = 0; v < 4; ++v)
        C[(size_t)(row + v) * N + col] = (OutT)acc[i][j][v];
    }
}

// ---------------- windowed attention ----------------
// one block = 4x4 guide tile (16 queries x 8 heads = 128 threads); 9 shared K/V rows
__global__ __launch_bounds__(128) void attn_win(const bf16_t* __restrict__ Q,
                                                const bf16_t* __restrict__ Kb,
                                                const bf16_t* __restrict__ Vb,
                                                bf16_t* __restrict__ Msg) {
  __shared__ __align__(16) bf16_t Kl[9 * 512];
  __shared__ __align__(16) bf16_t Vl[9 * 512];
  const int t = threadIdx.x;
  const int lane = t & 63;
  const int wave = t >> 6;
  const int tile = blockIdx.x;
  const int ty = tile >> 5, tx = tile & 31;
  for (int kk = wave; kk < 9; kk += 2) {
    int ky = kk / 3, kx = kk - ky * 3;
    int yy = min(max(ty - 1 + ky, 0), 31);
    int xx = min(max(tx - 1 + kx, 0), 31);
    size_t p = (size_t)(yy * 32 + xx) * 512;
    // interleaved LDS layout: [k][i8(8)][h(8)][e(8)] so heads hit distinct banks
    int dst = kk * 512 + (lane & 7) * 64 + (lane >> 3) * 8;
    *(bf16x8*)&Kl[dst] = *(const bf16x8*)&Kb[p + lane * 8];
    *(bf16x8*)&Vl[dst] = *(const bf16x8*)&Vb[p + lane * 8];
  }
  __syncthreads();
  const int pl = t >> 3, h = t & 7;
  const int y = ty * 4 + (pl >> 2), x = tx * 4 + (pl & 3);
  const size_t n = (size_t)y * 128 + x;
  const bf16_t* qrow = Q + n * 512 + h * 64;
  float s[9] = {};
#pragma unroll
  for (int i8 = 0; i8 < 8; ++i8) {
    bf16x8 q8 = *(const bf16x8*)(qrow + i8 * 8);
#pragma unroll
    for (int k = 0; k < 9; ++k) {
      bf16x8 k8 = *(const bf16x8*)&Kl[k * 512 + i8 * 64 + h * 8];
#pragma unroll
      for (int e = 0; e < 8; ++e) s[k] += (float)q8[e] * (float)k8[e];
    }
  }
  float mx = s[0];
#pragma unroll
  for (int k = 1; k < 9; ++k) mx = fmaxf(mx, s[k]);
  float sum = 0.f;
#pragma unroll
  for (int k = 0; k < 9; ++k) {
    s[k] = __expf((s[k] - mx) * 0.125f);
    sum += s[k];
  }
  const float inv = 1.0f / sum;
#pragma unroll
  for (int k = 0; k < 9; ++k) s[k] *= inv;
  bf16_t* orow = Msg + n * 512 + h * 64;
#pragma unroll
  for (int i8 = 0; i8 < 8; ++i8) {
    float accv[8] = {};
#pragma unroll
    for (int k = 0; k < 9; ++k) {
      bf16x8 v8 = *(const bf16x8*)&Vl[k * 512 + i8 * 64 + h * 8];
#pragma unroll
      for (int e = 0; e < 8; ++e) accv[e] += s[k] * (float)v8[e];
    }
    bf16x8 o;
#pragma unroll
    for (int e = 0; e < 8; ++e) o[e] = (bf16_t)accv[e];
    *(bf16x8*)&orow[i8 * 8] = o;
  }
}

// ---------------- LayerNorm stats: one wave per row ----------------
__global__ __launch_bounds__(256) void ln_stats(const float* __restrict__ P, float2* __restrict__ stats) {
  const int row = blockIdx.x * 4 + (threadIdx.x >> 6);
  const int lane = threadIdx.x & 63;
  const float4* p = (const float4*)(P + (size_t)row * 512);
  float s = 0.f, s2 = 0.f;
#pragma unroll
  for (int i = 0; i < 2; ++i) {
    float4 v = p[lane + i * 64];
    s += v.x + v.y + v.z + v.w;
    s2 += v.x * v.x + v.y * v.y + v.z * v.z + v.w * v.w;
  }
#pragma unroll
  for (int off = 32; off > 0; off >>= 1) {
    s += __shfl_down(s, off);
    s2 += __shfl_down(s2, off);
  }
  if (lane == 0) {
    float mu = s * (1.f / 512.f);
    float var = s2 * (1.f / 512.f) - mu * mu;
    stats[row] = make_float2(mu, rsqrtf(var + 1e-5f));
  }
}

// ---------------- apply LN + transpose to (d, H, W) ----------------
__global__ __launch_bounds__(256) void ln_transpose(const float* __restrict__ P,
                                                    const float2* __restrict__ stats,
                                                    const float* __restrict__ gamma,
                                                    const float* __restrict__ beta,
                                                    float* __restrict__ out) {
  __shared__ float tl[32][33];
  __shared__ float2 st[32];
  const int n0 = blockIdx.x * 32, j0 = blockIdx.y * 32;
  const int t = threadIdx.x, c = t & 31, r = t >> 5;
  if (t < 32) st[t] = stats[n0 + t];
  __syncthreads();
  const float g = gamma[j0 + c], b = beta[j0 + c];
#pragma unroll
  for (int it = 0; it < 4; ++it) {
    int rr = r + it * 8;  // n-within-tile
    float v = P[(size_t)(n0 + rr) * 512 + j0 + c];
    float2 ms = st[rr];
    tl[rr][c] = (v - ms.x) * ms.y * g + b;
  }
  __syncthreads();
#pragma unroll
  for (int it = 0; it < 4; ++it) {
    int rr = r + it * 8;  // j-within-tile
    out[(size_t)(j0 + rr) * NQ + n0 + c] = tl[c][rr];
  }
}

extern "C" void kernel_launch(void* const* d_in, const int* in_sizes, int n_in,
                              void* d_out, int out_size, void* d_ws, size_t ws_size,
                              hipStream_t stream) {
  const float* low = (const float*)d_in[0];
  const float* guide = (const float*)d_in[1];
  const float* Wq = (const float*)d_in[2];
  const float* Wk = (const float*)d_in[3];
  const float* Wv = (const float*)d_in[4];
  const float* Wm = (const float*)d_in[5];
  const float* gamma = (const float*)d_in[6];
  const float* beta = (const float*)d_in[7];
  float* out = (float*)d_out;

  char* w = (char*)d_ws;
  bf16_t* Gbf = (bf16_t*)w; w += (size_t)NQ * 512 * 2;
  bf16_t* Lbf = (bf16_t*)w; w += (size_t)NL * 512 * 2;
  bf16_t* Wqb = (bf16_t*)w; w += (size_t)512 * 512 * 2;
  bf16_t* Wkb = (bf16_t*)w; w += (size_t)512 * 512 * 2;
  bf16_t* Wvb = (bf16_t*)w; w += (size_t)512 * 512 * 2;
  bf16_t* Wmb = (bf16_t*)w; w += (size_t)512 * 512 * 2;
  bf16_t* Qbf = (bf16_t*)w; w += (size_t)NQ * 512 * 2;
  bf16_t* Kbf = (bf16_t*)w; w += (size_t)NL * 512 * 2;
  bf16_t* Vbf = (bf16_t*)w; w += (size_t)NL * 512 * 2;
  bf16_t* Msg = (bf16_t*)w; w += (size_t)NQ * 512 * 2;
  float* Pf = (float*)w;    w += (size_t)NQ * 512 * 4;
  float2* stats = (float2*)w;

  cvt_transpose<<<dim3(NQ / 32, 16), 256, 0, stream>>>(guide, Gbf, NQ);
  cvt_transpose<<<dim3(NL / 32, 16), 256, 0, stream>>>(low, Lbf, NL);
  cvt_w<<<dim3(256, 4), 256, 0, stream>>>(Wq, Wk, Wv, Wm, Wqb, Wkb, Wvb, Wmb);
  gemm_bt<bf16_t><<<dim3(NQ / 128, 4), 256, 0, stream>>>(Gbf, Wqb, Qbf, NQ, 512, 512);
  gemm_bt<bf16_t><<<dim3(NL / 128, 4), 256, 0, stream>>>(Lbf, Wkb, Kbf, NL, 512, 512);
  gemm_bt<bf16_t><<<dim3(NL / 128, 4), 256, 0, stream>>>(Lbf, Wvb, Vbf, NL, 512, 512);
  attn_win<<<dim3(1024), 128, 0, stream>>>(Qbf, Kbf, Vbf, Msg);
  gemm_bt<float><<<dim3(NQ / 128, 4), 256, 0, stream>>>(Msg, Wmb, Pf, NQ, 512, 512);
  ln_stats<<<dim3(NQ / 4), 256, 0, stream>>>(Pf, stats);
  ln_transpose<<<dim3(NQ / 32, 512 / 32), 256, 0, stream>>>(Pf, stats, gamma, beta, out);
}

// Round 3
// 174.545 us; speedup vs baseline: 1.1241x; 1.1241x over previous
//
#include <hip/hip_runtime.h>
#include <hip/hip_bf16.h>
#include <stdint.h>

#define NQ 16384   // 128*128 guide positions
#define NL 1024    // 32*32 low positions

typedef __bf16 bf16_t;
typedef __bf16 bf16x8 __attribute__((ext_vector_type(8)));
typedef __bf16 bf16x4 __attribute__((ext_vector_type(4)));
typedef float f32x4 __attribute__((ext_vector_type(4)));

__device__ __forceinline__ void gload_lds16(const void* g, void* l) {
  __builtin_amdgcn_global_load_lds(
      (const __attribute__((address_space(1))) uint32_t*)g,
      (__attribute__((address_space(3))) uint32_t*)l, 16, 0, 0);
}

// ---------------- transpose (d-major fp32) -> (n-major bf16), guide+low in one launch --------
__global__ __launch_bounds__(256) void cvt_transpose_all(const float* __restrict__ guide,
                                                         const float* __restrict__ low,
                                                         bf16_t* __restrict__ Gbf,
                                                         bf16_t* __restrict__ Lbf) {
  __shared__ float tl[32][33];
  const float* src;
  bf16_t* dst;
  int ncols, n0;
  if (blockIdx.x < 512) { src = guide; dst = Gbf; ncols = NQ; n0 = blockIdx.x * 32; }
  else                  { src = low;   dst = Lbf; ncols = NL; n0 = (blockIdx.x - 512) * 32; }
  const int c0 = blockIdx.y * 32;
  const int t = threadIdx.x, c = t & 31, r = t >> 5;  // r = 0..7
#pragma unroll
  for (int it = 0; it < 4; ++it) {
    int rr = r + it * 8;  // channel-within-tile
    tl[rr][c] = src[(size_t)(c0 + rr) * ncols + n0 + c];
  }
  __syncthreads();
#pragma unroll
  for (int it = 0; it < 4; ++it) {
    int rr = r + it * 8;  // n-within-tile
    dst[(size_t)(n0 + rr) * 512 + c0 + c] = (bf16_t)tl[c][rr];
  }
}

// ---------------- weights fp32 -> bf16; Wk/Wv go into one concatenated [1024][512] ----------
__global__ __launch_bounds__(256) void cvt_w(const float* __restrict__ s0, const float* __restrict__ s1,
                                             const float* __restrict__ s2, const float* __restrict__ s3,
                                             bf16_t* __restrict__ d0, bf16_t* __restrict__ d1,
                                             bf16_t* __restrict__ d2, bf16_t* __restrict__ d3) {
  const float* s;
  bf16_t* d;
  switch (blockIdx.y) {
    case 0: s = s0; d = d0; break;
    case 1: s = s1; d = d1; break;
    case 2: s = s2; d = d2; break;
    default: s = s3; d = d3; break;
  }
  const int i = (blockIdx.x * 256 + threadIdx.x) * 4;
  float4 v = *(const float4*)(s + i);
  bf16x4 o = {(bf16_t)v.x, (bf16_t)v.y, (bf16_t)v.z, (bf16_t)v.w};
  *(bf16x4*)(d + i) = o;
}

// ---------------- Q/K/V projections in ONE dispatch ----------------
// blocks [0,512): Q = Gbf @ Wq^T (16384x512); blocks [512,576): KV = Lbf @ [Wk;Wv]^T (1024x1024)
__global__ __launch_bounds__(256) void gemm_qkv(const bf16_t* __restrict__ G,
                                                const bf16_t* __restrict__ Wq,
                                                bf16_t* __restrict__ Qo,
                                                const bf16_t* __restrict__ L,
                                                const bf16_t* __restrict__ Wkv,
                                                bf16_t* __restrict__ KVo) {
  __shared__ __align__(16) bf16_t As[128 * 64];
  __shared__ __align__(16) bf16_t Bs[128 * 64];
  const bf16_t *A, *B;
  bf16_t* C;
  int N, bm, bn;
  const int bid = blockIdx.x;
  if (bid < 512) { A = G; B = Wq; C = Qo; N = 512; bm = (bid >> 2) * 128; bn = (bid & 3) * 128; }
  else { int id = bid - 512; A = L; B = Wkv; C = KVo; N = 1024; bm = (id >> 3) * 128; bn = (id & 7) * 128; }
  const int t = threadIdx.x;
  const int lane = t & 63;
  const int wave = t >> 6;
  const int wr = (wave >> 1) * 64;
  const int wc = (wave & 1) * 64;
  const int r0 = t >> 3;
  const int c0 = (t & 7) * 8;
  f32x4 acc[4][4] = {};
  for (int k0 = 0; k0 < 512; k0 += 64) {
#pragma unroll
    for (int it = 0; it < 4; ++it) {
      const int r = r0 + it * 32;
      gload_lds16(A + (size_t)(bm + r) * 512 + k0 + c0, &As[r * 64 + c0]);
      gload_lds16(B + (size_t)(bn + r) * 512 + k0 + c0, &Bs[r * 64 + c0]);
    }
    __syncthreads();
#pragma unroll
    for (int kk = 0; kk < 2; ++kk) {
      bf16x8 af[4], bfv[4];
#pragma unroll
      for (int i = 0; i < 4; ++i)
        af[i] = *(const bf16x8*)&As[(wr + i * 16 + (lane & 15)) * 64 + kk * 32 + (lane >> 4) * 8];
#pragma unroll
      for (int i = 0; i < 4; ++i)
        bfv[i] = *(const bf16x8*)&Bs[(wc + i * 16 + (lane & 15)) * 64 + kk * 32 + (lane >> 4) * 8];
#pragma unroll
      for (int i = 0; i < 4; ++i)
#pragma unroll
        for (int j = 0; j < 4; ++j)
          acc[i][j] = __builtin_amdgcn_mfma_f32_16x16x32_bf16(af[i], bfv[j], acc[i][j], 0, 0, 0);
    }
    __syncthreads();
  }
  const int crow = bm + wr + ((lane >> 4) * 4);
  const int ccol = bn + wc + (lane & 15);
#pragma unroll
  for (int i = 0; i < 4; ++i)
#pragma unroll
    for (int j = 0; j < 4; ++j) {
      const int row = crow + i * 16;
      const int col = ccol + j * 16;
#pragma unroll
      for (int v = 0; v < 4; ++v)
        C[(size_t)(row + v) * N + col] = (bf16_t)acc[i][j][v];
    }
}

// ---------------- windowed attention (reads concatenated KV) ----------------
__global__ __launch_bounds__(128) void attn_win(const bf16_t* __restrict__ Q,
                                                const bf16_t* __restrict__ KV,
                                                bf16_t* __restrict__ Msg) {
  __shared__ __align__(16) bf16_t Kl[9 * 512];
  __shared__ __align__(16) bf16_t Vl[9 * 512];
  const int t = threadIdx.x;
  const int lane = t & 63;
  const int wave = t >> 6;
  const int tile = blockIdx.x;
  const int ty = tile >> 5, tx = tile & 31;
  for (int kk = wave; kk < 9; kk += 2) {
    int ky = kk / 3, kx = kk - ky * 3;
    int yy = min(max(ty - 1 + ky, 0), 31);
    int xx = min(max(tx - 1 + kx, 0), 31);
    size_t p = (size_t)(yy * 32 + xx) * 1024;
    int dst = kk * 512 + (lane & 7) * 64 + (lane >> 3) * 8;  // [k][i8][h][8]
    *(bf16x8*)&Kl[dst] = *(const bf16x8*)&KV[p + lane * 8];
    *(bf16x8*)&Vl[dst] = *(const bf16x8*)&KV[p + 512 + lane * 8];
  }
  __syncthreads();
  const int pl = t >> 3, h = t & 7;
  const int y = ty * 4 + (pl >> 2), x = tx * 4 + (pl & 3);
  const size_t n = (size_t)y * 128 + x;
  const bf16_t* qrow = Q + n * 512 + h * 64;
  float s[9] = {};
#pragma unroll
  for (int i8 = 0; i8 < 8; ++i8) {
    bf16x8 q8 = *(const bf16x8*)(qrow + i8 * 8);
#pragma unroll
    for (int k = 0; k < 9; ++k) {
      bf16x8 k8 = *(const bf16x8*)&Kl[k * 512 + i8 * 64 + h * 8];
#pragma unroll
      for (int e = 0; e < 8; ++e) s[k] += (float)q8[e] * (float)k8[e];
    }
  }
  float mx = s[0];
#pragma unroll
  for (int k = 1; k < 9; ++k) mx = fmaxf(mx, s[k]);
  float sum = 0.f;
#pragma unroll
  for (int k = 0; k < 9; ++k) {
    s[k] = __expf((s[k] - mx) * 0.125f);
    sum += s[k];
  }
  const float inv = 1.0f / sum;
#pragma unroll
  for (int k = 0; k < 9; ++k) s[k] *= inv;
  bf16_t* orow = Msg + n * 512 + h * 64;
#pragma unroll
  for (int i8 = 0; i8 < 8; ++i8) {
    float accv[8] = {};
#pragma unroll
    for (int k = 0; k < 9; ++k) {
      bf16x8 v8 = *(const bf16x8*)&Vl[k * 512 + i8 * 64 + h * 8];
#pragma unroll
      for (int e = 0; e < 8; ++e) accv[e] += s[k] * (float)v8[e];
    }
    bf16x8 o;
#pragma unroll
    for (int e = 0; e < 8; ++e) o[e] = (bf16_t)accv[e];
    *(bf16x8*)&orow[i8 * 8] = o;
  }
}

// ---------------- fused: P = Msg @ Wm^T, LayerNorm over d, transposed write ----------------
// one block = 64 rows x all 512 cols; 8 waves: wave = (rowhalf<<2)|colquad
__global__ __launch_bounds__(512) void gemm_ln_out(const bf16_t* __restrict__ A,
                                                   const bf16_t* __restrict__ B,
                                                   const float* __restrict__ gamma,
                                                   const float* __restrict__ beta,
                                                   float* __restrict__ out) {
  __shared__ __align__(16) char smem[64 * 513 * 4];  // 131328 B; As/Bs overlay Cl
  __shared__ float2 part[64][4];
  __shared__ float2 st[64];
  bf16_t* As = (bf16_t*)smem;              // [64][64]  = 8 KB
  bf16_t* Bs = (bf16_t*)(smem + 8192);     // [512][64] = 64 KB
  float* Cl = (float*)smem;                // [64][513] fp32 (epilogue)
  const int t = threadIdx.x;
  const int lane = t & 63;
  const int wave = t >> 6;           // 0..7
  const int wr = (wave >> 2) * 32;   // row offset: 0 / 32
  const int wc = (wave & 3) * 128;   // col offset: 0..384
  const int bm = blockIdx.x * 64;
  const int sr = t >> 3;             // staging row 0..63
  const int sc = (t & 7) * 8;        // staging col
  f32x4 acc[2][8] = {};
  for (int k0 = 0; k0 < 512; k0 += 64) {
    gload_lds16(A + (size_t)(bm + sr) * 512 + k0 + sc, &As[sr * 64 + sc]);
#pragma unroll
    for (int it = 0; it < 8; ++it) {
      const int r = sr + it * 64;
      gload_lds16(B + (size_t)r * 512 + k0 + sc, &Bs[r * 64 + sc]);
    }
    __syncthreads();
#pragma unroll
    for (int kk = 0; kk < 2; ++kk) {
      bf16x8 af[2], bfv[8];
#pragma unroll
      for (int i = 0; i < 2; ++i)
        af[i] = *(const bf16x8*)&As[(wr + i * 16 + (lane & 15)) * 64 + kk * 32 + (lane >> 4) * 8];
#pragma unroll
      for (int j = 0; j < 8; ++j)
        bfv[j] = *(const bf16x8*)&Bs[(wc + j * 16 + (lane & 15)) * 64 + kk * 32 + (lane >> 4) * 8];
#pragma unroll
      for (int i = 0; i < 2; ++i)
#pragma unroll
        for (int j = 0; j < 8; ++j)
          acc[i][j] = __builtin_amdgcn_mfma_f32_16x16x32_bf16(af[i], bfv[j], acc[i][j], 0, 0, 0);
    }
    __syncthreads();
  }
  // spill accumulators to Cl[row][col] (pad 513 breaks bank alignment)
#pragma unroll
  for (int i = 0; i < 2; ++i)
#pragma unroll
    for (int j = 0; j < 8; ++j) {
      const int row = wr + i * 16 + (lane >> 4) * 4;
      const int col = wc + j * 16 + (lane & 15);
#pragma unroll
      for (int v = 0; v < 4; ++v) Cl[(row + v) * 513 + col] = acc[i][j][v];
    }
  // register-side LN partials: per thread, 8 rows x 8 cols
#pragma unroll
  for (int i = 0; i < 2; ++i)
#pragma unroll
    for (int v = 0; v < 4; ++v) {
      float s = 0.f, s2 = 0.f;
#pragma unroll
      for (int j = 0; j < 8; ++j) {
        float x = acc[i][j][v];
        s += x;
        s2 += x * x;
      }
#pragma unroll
      for (int m = 1; m < 16; m <<= 1) {  // reduce over the 16 col-lanes
        s += __shfl_xor(s, m, 64);
        s2 += __shfl_xor(s2, m, 64);
      }
      if ((lane & 15) == 0) {
        const int row = wr + i * 16 + (lane >> 4) * 4 + v;
        part[row][wave & 3] = make_float2(s, s2);
      }
    }
  __syncthreads();
  if (t < 64) {
    float2 p0 = part[t][0], p1 = part[t][1], p2 = part[t][2], p3 = part[t][3];
    float s = p0.x + p1.x + p2.x + p3.x;
    float s2 = p0.y + p1.y + p2.y + p3.y;
    float mu = s * (1.f / 512.f);
    float var = s2 * (1.f / 512.f) - mu * mu;
    st[t] = make_float2(mu, rsqrtf(var + 1e-5f));
  }
  __syncthreads();
  // apply LN + write transposed: out[j][bm+n]
  const int n = t & 63;
  const int j0 = t >> 6;
  const float2 ms = st[n];
#pragma unroll 8
  for (int jj = 0; jj < 64; ++jj) {
    const int j = j0 * 64 + jj;
    const float g = gamma[j], b = beta[j];
    const float x = Cl[n * 513 + j];
    out[(size_t)j * NQ + bm + n] = (x - ms.x) * ms.y * g + b;
  }
}

extern "C" void kernel_launch(void* const* d_in, const int* in_sizes, int n_in,
                              void* d_out, int out_size, void* d_ws, size_t ws_size,
                              hipStream_t stream) {
  const float* low = (const float*)d_in[0];
  const float* guide = (const float*)d_in[1];
  const float* Wq = (const float*)d_in[2];
  const float* Wk = (const float*)d_in[3];
  const float* Wv = (const float*)d_in[4];
  const float* Wm = (const float*)d_in[5];
  const float* gamma = (const float*)d_in[6];
  const float* beta = (const float*)d_in[7];
  float* out = (float*)d_out;

  char* w = (char*)d_ws;
  bf16_t* Gbf = (bf16_t*)w; w += (size_t)NQ * 512 * 2;
  bf16_t* Lbf = (bf16_t*)w; w += (size_t)NL * 512 * 2;
  bf16_t* Wqb = (bf16_t*)w; w += (size_t)512 * 512 * 2;
  bf16_t* Wkvb = (bf16_t*)w; w += (size_t)1024 * 512 * 2;
  bf16_t* Wmb = (bf16_t*)w; w += (size_t)512 * 512 * 2;
  bf16_t* Qbf = (bf16_t*)w; w += (size_t)NQ * 512 * 2;
  bf16_t* KVbf = (bf16_t*)w; w += (size_t)NL * 1024 * 2;
  bf16_t* Msg = (bf16_t*)w; w += (size_t)NQ * 512 * 2;

  cvt_transpose_all<<<dim3(544, 16), 256, 0, stream>>>(guide, low, Gbf, Lbf);
  cvt_w<<<dim3(256, 4), 256, 0, stream>>>(Wq, Wk, Wv, Wm, Wqb, Wkvb, Wkvb + (size_t)512 * 512, Wmb);
  gemm_qkv<<<dim3(576), 256, 0, stream>>>(Gbf, Wqb, Qbf, Lbf, Wkvb, KVbf);
  attn_win<<<dim3(1024), 128, 0, stream>>>(Qbf, KVbf, Msg);
  gemm_ln_out<<<dim3(NQ / 64), 512, 0, stream>>>(Msg, Wmb, gamma, beta, out);
}

// Round 4
// 168.891 us; speedup vs baseline: 1.1618x; 1.0335x over previous
//
#include <hip/hip_runtime.h>
#include <hip/hip_bf16.h>
#include <stdint.h>

#define NQ 16384   // 128*128 guide positions
#define NL 1024    // 32*32 low positions

typedef __bf16 bf16_t;
typedef __bf16 bf16x8 __attribute__((ext_vector_type(8)));
typedef __bf16 bf16x4 __attribute__((ext_vector_type(4)));
typedef float f32x4 __attribute__((ext_vector_type(4)));

__device__ __forceinline__ void gload_lds16(const void* g, void* l) {
  __builtin_amdgcn_global_load_lds(
      (const __attribute__((address_space(1))) uint32_t*)g,
      (__attribute__((address_space(3))) uint32_t*)l, 16, 0, 0);
}

// ---- transposes (d-major fp32 -> n-major bf16) + weight cvt, ONE launch ----
// bx<512: guide tiles; 512<=bx<544: low tiles; bx>=544: weight cvt (1024 blocks)
__global__ __launch_bounds__(256) void cvt_all(const float* __restrict__ guide,
                                               const float* __restrict__ low,
                                               const float* __restrict__ Wq,
                                               const float* __restrict__ Wk,
                                               const float* __restrict__ Wv,
                                               const float* __restrict__ Wm,
                                               bf16_t* __restrict__ Gbf,
                                               bf16_t* __restrict__ Lbf,
                                               bf16_t* __restrict__ Wall) {
  const int bx = blockIdx.x, by = blockIdx.y, t = threadIdx.x;
  if (bx >= 544) {
    const int idx = (((bx - 544) * 16 + by) * 256 + t) * 4;
    const float* s;
    int off;
    if (idx < 262144)      { s = Wq; off = idx; }
    else if (idx < 524288) { s = Wk; off = idx - 262144; }
    else if (idx < 786432) { s = Wv; off = idx - 524288; }
    else                   { s = Wm; off = idx - 786432; }
    float4 v = *(const float4*)(s + off);
    bf16x4 o = {(bf16_t)v.x, (bf16_t)v.y, (bf16_t)v.z, (bf16_t)v.w};
    *(bf16x4*)(Wall + idx) = o;
    return;
  }
  __shared__ float tl[32][33];
  const float* src;
  bf16_t* dst;
  int ncols, n0;
  if (bx < 512) { src = guide; dst = Gbf; ncols = NQ; n0 = bx * 32; }
  else          { src = low;   dst = Lbf; ncols = NL; n0 = (bx - 512) * 32; }
  const int c0 = by * 32;
  const int c = t & 31, r = t >> 5;
#pragma unroll
  for (int it = 0; it < 4; ++it) {
    int rr = r + it * 8;
    tl[rr][c] = src[(size_t)(c0 + rr) * ncols + n0 + c];
  }
  __syncthreads();
#pragma unroll
  for (int it = 0; it < 4; ++it) {
    int rr = r + it * 8;
    dst[(size_t)(n0 + rr) * 512 + c0 + c] = (bf16_t)tl[c][rr];
  }
}

// ---------------- Q/K/V projections, ONE dispatch, double-buffered LDS ----------------
// blocks [0,512): Q = Gbf @ Wq^T; blocks [512,576): KV = Lbf @ [Wk;Wv]^T
__global__ __launch_bounds__(256) void gemm_qkv(const bf16_t* __restrict__ G,
                                                const bf16_t* __restrict__ Wqb,
                                                bf16_t* __restrict__ Qo,
                                                const bf16_t* __restrict__ L,
                                                const bf16_t* __restrict__ Wkv,
                                                bf16_t* __restrict__ KVo) {
  __shared__ __align__(16) bf16_t As[2][128 * 64];
  __shared__ __align__(16) bf16_t Bs[2][128 * 64];
  const bf16_t *A, *B;
  bf16_t* C;
  int N, bm, bn;
  const int bid = blockIdx.x;
  if (bid < 512) { A = G; B = Wqb; C = Qo; N = 512; bm = (bid >> 2) * 128; bn = (bid & 3) * 128; }
  else { int id = bid - 512; A = L; B = Wkv; C = KVo; N = 1024; bm = (id >> 3) * 128; bn = (id & 7) * 128; }
  const int t = threadIdx.x;
  const int lane = t & 63;
  const int wave = t >> 6;
  const int wr = (wave >> 1) * 64;
  const int wc = (wave & 1) * 64;
  const int r0 = t >> 3;
  const int c0 = (t & 7) * 8;
  const int fr = lane & 15;
  const int fk = (lane >> 4) * 8;
  // prologue: stage K-tile 0 into buffer 0
#pragma unroll
  for (int it = 0; it < 4; ++it) {
    const int r = r0 + it * 32;
    gload_lds16(A + (size_t)(bm + r) * 512 + c0, &As[0][r * 64 + c0]);
    gload_lds16(B + (size_t)(bn + r) * 512 + c0, &Bs[0][r * 64 + c0]);
  }
  f32x4 acc[4][4] = {};
  __syncthreads();
#pragma unroll 2
  for (int kt = 0; kt < 8; ++kt) {
    const int cur = kt & 1;
    if (kt < 7) {  // issue next-tile stage BEFORE computing current (2-phase)
      const int k0 = (kt + 1) * 64;
#pragma unroll
      for (int it = 0; it < 4; ++it) {
        const int r = r0 + it * 32;
        gload_lds16(A + (size_t)(bm + r) * 512 + k0 + c0, &As[cur ^ 1][r * 64 + c0]);
        gload_lds16(B + (size_t)(bn + r) * 512 + k0 + c0, &Bs[cur ^ 1][r * 64 + c0]);
      }
    }
    __builtin_amdgcn_sched_barrier(0);
#pragma unroll
    for (int kk = 0; kk < 2; ++kk) {
      bf16x8 af[4], bfv[4];
#pragma unroll
      for (int i = 0; i < 4; ++i)
        af[i] = *(const bf16x8*)&As[cur][(wr + i * 16 + fr) * 64 + kk * 32 + fk];
#pragma unroll
      for (int i = 0; i < 4; ++i)
        bfv[i] = *(const bf16x8*)&Bs[cur][(wc + i * 16 + fr) * 64 + kk * 32 + fk];
#pragma unroll
      for (int i = 0; i < 4; ++i)
#pragma unroll
        for (int j = 0; j < 4; ++j)
          acc[i][j] = __builtin_amdgcn_mfma_f32_16x16x32_bf16(af[i], bfv[j], acc[i][j], 0, 0, 0);
    }
    __syncthreads();  // vmcnt(0) drain covers the prefetch issued above
  }
  const int crow = bm + wr + ((lane >> 4) * 4);
  const int ccol = bn + wc + fr;
#pragma unroll
  for (int i = 0; i < 4; ++i)
#pragma unroll
    for (int j = 0; j < 4; ++j) {
      const int row = crow + i * 16;
      const int col = ccol + j * 16;
#pragma unroll
      for (int v = 0; v < 4; ++v)
        C[(size_t)(row + v) * N + col] = (bf16_t)acc[i][j][v];
    }
}

// ---------------- windowed attention (reads concatenated KV) ----------------
__global__ __launch_bounds__(128) void attn_win(const bf16_t* __restrict__ Q,
                                                const bf16_t* __restrict__ KV,
                                                bf16_t* __restrict__ Msg) {
  __shared__ __align__(16) bf16_t Kl[9 * 512];
  __shared__ __align__(16) bf16_t Vl[9 * 512];
  const int t = threadIdx.x;
  const int lane = t & 63;
  const int wave = t >> 6;
  const int tile = blockIdx.x;
  const int ty = tile >> 5, tx = tile & 31;
  for (int kk = wave; kk < 9; kk += 2) {
    int ky = kk / 3, kx = kk - ky * 3;
    int yy = min(max(ty - 1 + ky, 0), 31);
    int xx = min(max(tx - 1 + kx, 0), 31);
    size_t p = (size_t)(yy * 32 + xx) * 1024;
    int dst = kk * 512 + (lane & 7) * 64 + (lane >> 3) * 8;  // [k][i8][h][8]
    *(bf16x8*)&Kl[dst] = *(const bf16x8*)&KV[p + lane * 8];
    *(bf16x8*)&Vl[dst] = *(const bf16x8*)&KV[p + 512 + lane * 8];
  }
  __syncthreads();
  const int pl = t >> 3, h = t & 7;
  const int y = ty * 4 + (pl >> 2), x = tx * 4 + (pl & 3);
  const size_t n = (size_t)y * 128 + x;
  const bf16_t* qrow = Q + n * 512 + h * 64;
  float s[9] = {};
#pragma unroll
  for (int i8 = 0; i8 < 8; ++i8) {
    bf16x8 q8 = *(const bf16x8*)(qrow + i8 * 8);
#pragma unroll
    for (int k = 0; k < 9; ++k) {
      bf16x8 k8 = *(const bf16x8*)&Kl[k * 512 + i8 * 64 + h * 8];
#pragma unroll
      for (int e = 0; e < 8; ++e) s[k] += (float)q8[e] * (float)k8[e];
    }
  }
  float mx = s[0];
#pragma unroll
  for (int k = 1; k < 9; ++k) mx = fmaxf(mx, s[k]);
  float sum = 0.f;
#pragma unroll
  for (int k = 0; k < 9; ++k) {
    s[k] = __expf((s[k] - mx) * 0.125f);
    sum += s[k];
  }
  const float inv = 1.0f / sum;
#pragma unroll
  for (int k = 0; k < 9; ++k) s[k] *= inv;
  bf16_t* orow = Msg + n * 512 + h * 64;
#pragma unroll
  for (int i8 = 0; i8 < 8; ++i8) {
    float accv[8] = {};
#pragma unroll
    for (int k = 0; k < 9; ++k) {
      bf16x8 v8 = *(const bf16x8*)&Vl[k * 512 + i8 * 64 + h * 8];
#pragma unroll
      for (int e = 0; e < 8; ++e) accv[e] += s[k] * (float)v8[e];
    }
    bf16x8 o;
#pragma unroll
    for (int e = 0; e < 8; ++e) o[e] = (bf16_t)accv[e];
    *(bf16x8*)&orow[i8 * 8] = o;
  }
}

// ------- fused: P = Msg @ Wm^T, LayerNorm over d, transposed write; dbuf LDS -------
__global__ __launch_bounds__(512) void gemm_ln_out(const bf16_t* __restrict__ A,
                                                   const bf16_t* __restrict__ B,
                                                   const float* __restrict__ gamma,
                                                   const float* __restrict__ beta,
                                                   float* __restrict__ out) {
  __shared__ __align__(16) char smem[147456];  // As0|As1|Bs0|Bs1; Cl overlays after loop
  __shared__ float2 part[64][4];
  __shared__ float2 st[64];
  bf16_t* const As0 = (bf16_t*)smem;              // 8 KB
  bf16_t* const As1 = (bf16_t*)(smem + 8192);     // 8 KB
  bf16_t* const Bs0 = (bf16_t*)(smem + 16384);    // 64 KB
  bf16_t* const Bs1 = (bf16_t*)(smem + 81920);    // 64 KB
  float* const Cl = (float*)smem;                 // [64][513] fp32 (epilogue)
  const int t = threadIdx.x;
  const int lane = t & 63;
  const int wave = t >> 6;           // 0..7
  const int wr = (wave >> 2) * 32;   // row offset: 0 / 32
  const int wc = (wave & 3) * 128;   // col offset: 0..384
  const int bm = blockIdx.x * 64;
  const int sr = t >> 3;             // staging row 0..63
  const int sc = (t & 7) * 8;        // staging col
  const int fr = lane & 15;
  const int fk = (lane >> 4) * 8;
  // prologue: stage K-tile 0
  gload_lds16(A + (size_t)(bm + sr) * 512 + sc, &As0[sr * 64 + sc]);
#pragma unroll
  for (int it = 0; it < 8; ++it) {
    const int r = sr + it * 64;
    gload_lds16(B + (size_t)r * 512 + sc, &Bs0[r * 64 + sc]);
  }
  f32x4 acc[2][8] = {};
  __syncthreads();
#pragma unroll 2
  for (int kt = 0; kt < 8; ++kt) {
    bf16_t* const Asc = (kt & 1) ? As1 : As0;
    bf16_t* const Bsc = (kt & 1) ? Bs1 : Bs0;
    bf16_t* const Asn = (kt & 1) ? As0 : As1;
    bf16_t* const Bsn = (kt & 1) ? Bs0 : Bs1;
    if (kt < 7) {
      const int k0 = (kt + 1) * 64;
      gload_lds16(A + (size_t)(bm + sr) * 512 + k0 + sc, &Asn[sr * 64 + sc]);
#pragma unroll
      for (int it = 0; it < 8; ++it) {
        const int r = sr + it * 64;
        gload_lds16(B + (size_t)r * 512 + k0 + sc, &Bsn[r * 64 + sc]);
      }
    }
    __builtin_amdgcn_sched_barrier(0);
#pragma unroll
    for (int kk = 0; kk < 2; ++kk) {
      bf16x8 af[2], bfv[8];
#pragma unroll
      for (int i = 0; i < 2; ++i)
        af[i] = *(const bf16x8*)&Asc[(wr + i * 16 + fr) * 64 + kk * 32 + fk];
#pragma unroll
      for (int j = 0; j < 8; ++j)
        bfv[j] = *(const bf16x8*)&Bsc[(wc + j * 16 + fr) * 64 + kk * 32 + fk];
#pragma unroll
      for (int i = 0; i < 2; ++i)
#pragma unroll
        for (int j = 0; j < 8; ++j)
          acc[i][j] = __builtin_amdgcn_mfma_f32_16x16x32_bf16(af[i], bfv[j], acc[i][j], 0, 0, 0);
    }
    __syncthreads();
  }
  // spill accumulators to Cl[row][col]
#pragma unroll
  for (int i = 0; i < 2; ++i)
#pragma unroll
    for (int j = 0; j < 8; ++j) {
      const int row = wr + i * 16 + (lane >> 4) * 4;
      const int col = wc + j * 16 + fr;
#pragma unroll
      for (int v = 0; v < 4; ++v) Cl[(row + v) * 513 + col] = acc[i][j][v];
    }
  // LN partials from registers
#pragma unroll
  for (int i = 0; i < 2; ++i)
#pragma unroll
    for (int v = 0; v < 4; ++v) {
      float s = 0.f, s2 = 0.f;
#pragma unroll
      for (int j = 0; j < 8; ++j) {
        float x = acc[i][j][v];
        s += x;
        s2 += x * x;
      }
#pragma unroll
      for (int m = 1; m < 16; m <<= 1) {
        s += __shfl_xor(s, m, 64);
        s2 += __shfl_xor(s2, m, 64);
      }
      if ((lane & 15) == 0) {
        const int row = wr + i * 16 + (lane >> 4) * 4 + v;
        part[row][wave & 3] = make_float2(s, s2);
      }
    }
  __syncthreads();
  if (t < 64) {
    float2 p0 = part[t][0], p1 = part[t][1], p2 = part[t][2], p3 = part[t][3];
    float s = p0.x + p1.x + p2.x + p3.x;
    float s2 = p0.y + p1.y + p2.y + p3.y;
    float mu = s * (1.f / 512.f);
    float var = s2 * (1.f / 512.f) - mu * mu;
    st[t] = make_float2(mu, rsqrtf(var + 1e-5f));
  }
  __syncthreads();
  const int n = t & 63;
  const int j0 = t >> 6;
  const float2 ms = st[n];
#pragma unroll 8
  for (int jj = 0; jj < 64; ++jj) {
    const int j = j0 * 64 + jj;
    const float g = gamma[j], b = beta[j];
    const float x = Cl[n * 513 + j];
    out[(size_t)j * NQ + bm + n] = (x - ms.x) * ms.y * g + b;
  }
}

extern "C" void kernel_launch(void* const* d_in, const int* in_sizes, int n_in,
                              void* d_out, int out_size, void* d_ws, size_t ws_size,
                              hipStream_t stream) {
  const float* low = (const float*)d_in[0];
  const float* guide = (const float*)d_in[1];
  const float* Wq = (const float*)d_in[2];
  const float* Wk = (const float*)d_in[3];
  const float* Wv = (const float*)d_in[4];
  const float* Wm = (const float*)d_in[5];
  const float* gamma = (const float*)d_in[6];
  const float* beta = (const float*)d_in[7];
  float* out = (float*)d_out;

  char* w = (char*)d_ws;
  bf16_t* Gbf = (bf16_t*)w;  w += (size_t)NQ * 512 * 2;
  bf16_t* Lbf = (bf16_t*)w;  w += (size_t)NL * 512 * 2;
  bf16_t* Wall = (bf16_t*)w; w += (size_t)4 * 512 * 512 * 2;  // Wq|Wk|Wv|Wm contiguous
  bf16_t* Qbf = (bf16_t*)w;  w += (size_t)NQ * 512 * 2;
  bf16_t* KVbf = (bf16_t*)w; w += (size_t)NL * 1024 * 2;
  bf16_t* Msg = (bf16_t*)w;  w += (size_t)NQ * 512 * 2;

  cvt_all<<<dim3(608, 16), 256, 0, stream>>>(guide, low, Wq, Wk, Wv, Wm, Gbf, Lbf, Wall);
  gemm_qkv<<<dim3(576), 256, 0, stream>>>(Gbf, Wall, Qbf, Lbf, Wall + 262144, KVbf);
  attn_win<<<dim3(1024), 128, 0, stream>>>(Qbf, KVbf, Msg);
  gemm_ln_out<<<dim3(NQ / 64), 512, 0, stream>>>(Msg, Wall + 786432, gamma, beta, out);
}

// Round 6
// 165.944 us; speedup vs baseline: 1.1824x; 1.0178x over previous
//
#include <hip/hip_runtime.h>
#include <hip/hip_bf16.h>
#include <stdint.h>

#define NQ 16384   // 128*128 guide positions
#define NL 1024    // 32*32 low positions

typedef __bf16 bf16_t;
typedef __bf16 bf16x8 __attribute__((ext_vector_type(8)));
typedef __bf16 bf16x4 __attribute__((ext_vector_type(4)));
typedef float f32x4 __attribute__((ext_vector_type(4)));

__device__ __forceinline__ void gload_lds16(const void* g, void* l) {
  __builtin_amdgcn_global_load_lds(
      (const __attribute__((address_space(1))) uint32_t*)g,
      (__attribute__((address_space(3))) uint32_t*)l, 16, 0, 0);
}

// ---- transposes (d-major fp32 -> n-major bf16) + weight cvt, ONE launch ----
// bx<512: guide tiles; 512<=bx<544: low tiles; bx>=544: weight cvt (1024 blocks)
__global__ __launch_bounds__(256) void cvt_all(const float* __restrict__ guide,
                                               const float* __restrict__ low,
                                               const float* __restrict__ Wq,
                                               const float* __restrict__ Wk,
                                               const float* __restrict__ Wv,
                                               const float* __restrict__ Wm,
                                               bf16_t* __restrict__ Gbf,
                                               bf16_t* __restrict__ Lbf,
                                               bf16_t* __restrict__ Wall) {
  const int bx = blockIdx.x, by = blockIdx.y, t = threadIdx.x;
  if (bx >= 544) {
    const int idx = (((bx - 544) * 16 + by) * 256 + t) * 4;
    const float* s;
    int off;
    if (idx < 262144)      { s = Wq; off = idx; }
    else if (idx < 524288) { s = Wk; off = idx - 262144; }
    else if (idx < 786432) { s = Wv; off = idx - 524288; }
    else                   { s = Wm; off = idx - 786432; }
    float4 v = *(const float4*)(s + off);
    bf16x4 o = {(bf16_t)v.x, (bf16_t)v.y, (bf16_t)v.z, (bf16_t)v.w};
    *(bf16x4*)(Wall + idx) = o;
    return;
  }
  __shared__ float tl[32][33];
  const float* src;
  bf16_t* dst;
  int ncols, n0;
  if (bx < 512) { src = guide; dst = Gbf; ncols = NQ; n0 = bx * 32; }
  else          { src = low;   dst = Lbf; ncols = NL; n0 = (bx - 512) * 32; }
  const int c0 = by * 32;
  const int c = t & 31, r = t >> 5;
#pragma unroll
  for (int it = 0; it < 4; ++it) {
    int rr = r + it * 8;
    tl[rr][c] = src[(size_t)(c0 + rr) * ncols + n0 + c];
  }
  __syncthreads();
#pragma unroll
  for (int it = 0; it < 4; ++it) {
    int rr = r + it * 8;
    dst[(size_t)(n0 + rr) * 512 + c0 + c] = (bf16_t)tl[c][rr];
  }
}

// ---------------- Q/K/V projections, ONE dispatch, double-buffered LDS ----------------
// blocks [0,512): Q = Gbf @ Wq^T; blocks [512,576): KV = Lbf @ [Wk;Wv]^T
__global__ __launch_bounds__(256) void gemm_qkv(const bf16_t* __restrict__ G,
                                                const bf16_t* __restrict__ Wqb,
                                                bf16_t* __restrict__ Qo,
                                                const bf16_t* __restrict__ L,
                                                const bf16_t* __restrict__ Wkv,
                                                bf16_t* __restrict__ KVo) {
  __shared__ __align__(16) bf16_t As[2][128 * 64];
  __shared__ __align__(16) bf16_t Bs[2][128 * 64];
  const bf16_t *A, *B;
  bf16_t* C;
  int N, bm, bn;
  const int bid = blockIdx.x;
  if (bid < 512) { A = G; B = Wqb; C = Qo; N = 512; bm = (bid >> 2) * 128; bn = (bid & 3) * 128; }
  else { int id = bid - 512; A = L; B = Wkv; C = KVo; N = 1024; bm = (id >> 3) * 128; bn = (id & 7) * 128; }
  const int t = threadIdx.x;
  const int lane = t & 63;
  const int wave = t >> 6;
  const int wr = (wave >> 1) * 64;
  const int wc = (wave & 1) * 64;
  const int r0 = t >> 3;
  const int c0 = (t & 7) * 8;
  const int fr = lane & 15;
  const int fk = (lane >> 4) * 8;
  // prologue: stage K-tile 0 into buffer 0
#pragma unroll
  for (int it = 0; it < 4; ++it) {
    const int r = r0 + it * 32;
    gload_lds16(A + (size_t)(bm + r) * 512 + c0, &As[0][r * 64 + c0]);
    gload_lds16(B + (size_t)(bn + r) * 512 + c0, &Bs[0][r * 64 + c0]);
  }
  f32x4 acc[4][4] = {};
  __syncthreads();
#pragma unroll 2
  for (int kt = 0; kt < 8; ++kt) {
    const int cur = kt & 1;
    if (kt < 7) {  // issue next-tile stage BEFORE computing current (2-phase)
      const int k0 = (kt + 1) * 64;
#pragma unroll
      for (int it = 0; it < 4; ++it) {
        const int r = r0 + it * 32;
        gload_lds16(A + (size_t)(bm + r) * 512 + k0 + c0, &As[cur ^ 1][r * 64 + c0]);
        gload_lds16(B + (size_t)(bn + r) * 512 + k0 + c0, &Bs[cur ^ 1][r * 64 + c0]);
      }
    }
    __builtin_amdgcn_sched_barrier(0);
#pragma unroll
    for (int kk = 0; kk < 2; ++kk) {
      bf16x8 af[4], bfv[4];
#pragma unroll
      for (int i = 0; i < 4; ++i)
        af[i] = *(const bf16x8*)&As[cur][(wr + i * 16 + fr) * 64 + kk * 32 + fk];
#pragma unroll
      for (int i = 0; i < 4; ++i)
        bfv[i] = *(const bf16x8*)&Bs[cur][(wc + i * 16 + fr) * 64 + kk * 32 + fk];
#pragma unroll
      for (int i = 0; i < 4; ++i)
#pragma unroll
        for (int j = 0; j < 4; ++j)
          acc[i][j] = __builtin_amdgcn_mfma_f32_16x16x32_bf16(af[i], bfv[j], acc[i][j], 0, 0, 0);
    }
    __syncthreads();  // vmcnt(0) drain covers the prefetch issued above
  }
  const int crow = bm + wr + ((lane >> 4) * 4);
  const int ccol = bn + wc + fr;
#pragma unroll
  for (int i = 0; i < 4; ++i)
#pragma unroll
    for (int j = 0; j < 4; ++j) {
      const int row = crow + i * 16;
      const int col = ccol + j * 16;
#pragma unroll
      for (int v = 0; v < 4; ++v)
        C[(size_t)(row + v) * N + col] = (bf16_t)acc[i][j][v];
    }
}

// ---------------- windowed attention, 512 threads/block ----------------
// thread = (query pl 0..15, head h 0..7, dim-chunk c 0..3); 8 waves; plain [k][512] LDS
__global__ __launch_bounds__(512) void attn_win(const bf16_t* __restrict__ Q,
                                                const bf16_t* __restrict__ KV,
                                                bf16_t* __restrict__ Msg) {
  __shared__ __align__(16) bf16_t Kl[9 * 512];
  __shared__ __align__(16) bf16_t Vl[9 * 512];
  const int t = threadIdx.x;
  const int lane = t & 63;
  const int wave = t >> 6;
  const int tile = blockIdx.x;
  const int ty = tile >> 5, tx = tile & 31;
  // stage: wave w -> window row kk=w (wave 0 also kk=8); lane-contiguous b128 writes
  for (int kk = wave; kk < 9; kk += 8) {
    int ky = kk / 3, kx = kk - ky * 3;
    int yy = min(max(ty - 1 + ky, 0), 31);
    int xx = min(max(tx - 1 + kx, 0), 31);
    size_t p = (size_t)(yy * 32 + xx) * 1024;
    *(bf16x8*)&Kl[kk * 512 + lane * 8] = *(const bf16x8*)&KV[p + lane * 8];
    *(bf16x8*)&Vl[kk * 512 + lane * 8] = *(const bf16x8*)&KV[p + 512 + lane * 8];
  }
  __syncthreads();
  const int c = t & 3;            // 16-dim chunk
  const int h = (t >> 2) & 7;     // head
  const int pl = t >> 5;          // query within 4x4 tile
  const int y = ty * 4 + (pl >> 2), x = tx * 4 + (pl & 3);
  const size_t n = (size_t)y * 128 + x;
  const int doff = h * 64 + c * 16;  // this thread's 16 dims
  const bf16x8 q0 = *(const bf16x8*)(Q + n * 512 + doff);
  const bf16x8 q1 = *(const bf16x8*)(Q + n * 512 + doff + 8);
  float s[9];
#pragma unroll
  for (int k = 0; k < 9; ++k) {
    bf16x8 k0 = *(const bf16x8*)&Kl[k * 512 + doff];
    bf16x8 k1 = *(const bf16x8*)&Kl[k * 512 + doff + 8];
    float p = 0.f;
#pragma unroll
    for (int e = 0; e < 8; ++e) p += (float)q0[e] * (float)k0[e] + (float)q1[e] * (float)k1[e];
    // reduce the 4-chunk group (lanes differing in bits 0..1)
    p += __shfl_xor(p, 1, 64);
    p += __shfl_xor(p, 2, 64);
    s[k] = p;
  }
  float mx = s[0];
#pragma unroll
  for (int k = 1; k < 9; ++k) mx = fmaxf(mx, s[k]);
  float sum = 0.f;
#pragma unroll
  for (int k = 0; k < 9; ++k) {
    s[k] = __expf((s[k] - mx) * 0.125f);
    sum += s[k];
  }
  const float inv = 1.0f / sum;
  float acc[16] = {};
#pragma unroll
  for (int k = 0; k < 9; ++k) {
    const float p = s[k] * inv;
    bf16x8 v0 = *(const bf16x8*)&Vl[k * 512 + doff];
    bf16x8 v1 = *(const bf16x8*)&Vl[k * 512 + doff + 8];
#pragma unroll
    for (int e = 0; e < 8; ++e) {
      acc[e] += p * (float)v0[e];
      acc[8 + e] += p * (float)v1[e];
    }
  }
  bf16x8 o0, o1;
#pragma unroll
  for (int e = 0; e < 8; ++e) { o0[e] = (bf16_t)acc[e]; o1[e] = (bf16_t)acc[8 + e]; }
  *(bf16x8*)(Msg + n * 512 + doff) = o0;
  *(bf16x8*)(Msg + n * 512 + doff + 8) = o1;
}

// ------- fused: P = Msg @ Wm^T, LayerNorm over d, transposed write; dbuf LDS -------
__global__ __launch_bounds__(512) void gemm_ln_out(const bf16_t* __restrict__ A,
                                                   const bf16_t* __restrict__ B,
                                                   const float* __restrict__ gamma,
                                                   const float* __restrict__ beta,
                                                   float* __restrict__ out) {
  __shared__ __align__(16) char smem[147456];  // As0|As1|Bs0|Bs1; Cl overlays after loop
  __shared__ float2 part[64][4];
  __shared__ float2 st[64];
  bf16_t* const As0 = (bf16_t*)smem;              // 8 KB
  bf16_t* const As1 = (bf16_t*)(smem + 8192);     // 8 KB
  bf16_t* const Bs0 = (bf16_t*)(smem + 16384);    // 64 KB
  bf16_t* const Bs1 = (bf16_t*)(smem + 81920);    // 64 KB
  float* const Cl = (float*)smem;                 // [64][513] fp32 (epilogue)
  const int t = threadIdx.x;
  const int lane = t & 63;
  const int wave = t >> 6;           // 0..7
  const int wr = (wave >> 2) * 32;   // row offset: 0 / 32
  const int wc = (wave & 3) * 128;   // col offset: 0..384
  const int bm = blockIdx.x * 64;
  const int sr = t >> 3;             // staging row 0..63
  const int sc = (t & 7) * 8;        // staging col
  const int fr = lane & 15;
  const int fk = (lane >> 4) * 8;
  // prologue: stage K-tile 0
  gload_lds16(A + (size_t)(bm + sr) * 512 + sc, &As0[sr * 64 + sc]);
#pragma unroll
  for (int it = 0; it < 8; ++it) {
    const int r = sr + it * 64;
    gload_lds16(B + (size_t)r * 512 + sc, &Bs0[r * 64 + sc]);
  }
  f32x4 acc[2][8] = {};
  __syncthreads();
#pragma unroll 2
  for (int kt = 0; kt < 8; ++kt) {
    bf16_t* const Asc = (kt & 1) ? As1 : As0;
    bf16_t* const Bsc = (kt & 1) ? Bs1 : Bs0;
    bf16_t* const Asn = (kt & 1) ? As0 : As1;
    bf16_t* const Bsn = (kt & 1) ? Bs0 : Bs1;
    if (kt < 7) {
      const int k0 = (kt + 1) * 64;
      gload_lds16(A + (size_t)(bm + sr) * 512 + k0 + sc, &Asn[sr * 64 + sc]);
#pragma unroll
      for (int it = 0; it < 8; ++it) {
        const int r = sr + it * 64;
        gload_lds16(B + (size_t)r * 512 + k0 + sc, &Bsn[r * 64 + sc]);
      }
    }
    __builtin_amdgcn_sched_barrier(0);
#pragma unroll
    for (int kk = 0; kk < 2; ++kk) {
      bf16x8 af[2], bfv[8];
#pragma unroll
      for (int i = 0; i < 2; ++i)
        af[i] = *(const bf16x8*)&Asc[(wr + i * 16 + fr) * 64 + kk * 32 + fk];
#pragma unroll
      for (int j = 0; j < 8; ++j)
        bfv[j] = *(const bf16x8*)&Bsc[(wc + j * 16 + fr) * 64 + kk * 32 + fk];
#pragma unroll
      for (int i = 0; i < 2; ++i)
#pragma unroll
        for (int j = 0; j < 8; ++j)
          acc[i][j] = __builtin_amdgcn_mfma_f32_16x16x32_bf16(af[i], bfv[j], acc[i][j], 0, 0, 0);
    }
    __syncthreads();
  }
  // spill accumulators to Cl[row][col]
#pragma unroll
  for (int i = 0; i < 2; ++i)
#pragma unroll
    for (int j = 0; j < 8; ++j) {
      const int row = wr + i * 16 + (lane >> 4) * 4;
      const int col = wc + j * 16 + fr;
#pragma unroll
      for (int v = 0; v < 4; ++v) Cl[(row + v) * 513 + col] = acc[i][j][v];
    }
  // LN partials from registers
#pragma unroll
  for (int i = 0; i < 2; ++i)
#pragma unroll
    for (int v = 0; v < 4; ++v) {
      float s = 0.f, s2 = 0.f;
#pragma unroll
      for (int j = 0; j < 8; ++j) {
        float x = acc[i][j][v];
        s += x;
        s2 += x * x;
      }
#pragma unroll
      for (int m = 1; m < 16; m <<= 1) {
        s += __shfl_xor(s, m, 64);
        s2 += __shfl_xor(s2, m, 64);
      }
      if ((lane & 15) == 0) {
        const int row = wr + i * 16 + (lane >> 4) * 4 + v;
        part[row][wave & 3] = make_float2(s, s2);
      }
    }
  __syncthreads();
  if (t < 64) {
    float2 p0 = part[t][0], p1 = part[t][1], p2 = part[t][2], p3 = part[t][3];
    float s = p0.x + p1.x + p2.x + p3.x;
    float s2 = p0.y + p1.y + p2.y + p3.y;
    float mu = s * (1.f / 512.f);
    float var = s2 * (1.f / 512.f) - mu * mu;
    st[t] = make_float2(mu, rsqrtf(var + 1e-5f));
  }
  __syncthreads();
  const int n = t & 63;
  const int j0 = t >> 6;
  const float2 ms = st[n];
#pragma unroll 8
  for (int jj = 0; jj < 64; ++jj) {
    const int j = j0 * 64 + jj;
    const float g = gamma[j], b = beta[j];
    const float x = Cl[n * 513 + j];
    out[(size_t)j * NQ + bm + n] = (x - ms.x) * ms.y * g + b;
  }
}

extern "C" void kernel_launch(void* const* d_in, const int* in_sizes, int n_in,
                              void* d_out, int out_size, void* d_ws, size_t ws_size,
                              hipStream_t stream) {
  const float* low = (const float*)d_in[0];
  const float* guide = (const float*)d_in[1];
  const float* Wq = (const float*)d_in[2];
  const float* Wk = (const float*)d_in[3];
  const float* Wv = (const float*)d_in[4];
  const float* Wm = (const float*)d_in[5];
  const float* gamma = (const float*)d_in[6];
  const float* beta = (const float*)d_in[7];
  float* out = (float*)d_out;

  char* w = (char*)d_ws;
  bf16_t* Gbf = (bf16_t*)w;  w += (size_t)NQ * 512 * 2;
  bf16_t* Lbf = (bf16_t*)w;  w += (size_t)NL * 512 * 2;
  bf16_t* Wall = (bf16_t*)w; w += (size_t)4 * 512 * 512 * 2;  // Wq|Wk|Wv|Wm contiguous
  bf16_t* Qbf = (bf16_t*)w;  w += (size_t)NQ * 512 * 2;
  bf16_t* KVbf = (bf16_t*)w; w += (size_t)NL * 1024 * 2;
  bf16_t* Msg = (bf16_t*)w;  w += (size_t)NQ * 512 * 2;

  cvt_all<<<dim3(608, 16), 256, 0, stream>>>(guide, low, Wq, Wk, Wv, Wm, Gbf, Lbf, Wall);
  gemm_qkv<<<dim3(576), 256, 0, stream>>>(Gbf, Wall, Qbf, Lbf, Wall + 262144, KVbf);
  attn_win<<<dim3(1024), 512, 0, stream>>>(Qbf, KVbf, Msg);
  gemm_ln_out<<<dim3(NQ / 64), 512, 0, stream>>>(Msg, Wall + 786432, gamma, beta, out);
}